// Round 20
// baseline (127.700 us; speedup 1.0000x reference)
//
#include <hip/hip_runtime.h>
#include <hip/hip_bf16.h>
#include <stdint.h>
#include <stddef.h>

typedef __bf16 bf16x8 __attribute__((ext_vector_type(8)));
typedef __bf16 bf16x4 __attribute__((ext_vector_type(4)));
typedef float  f32x4  __attribute__((ext_vector_type(4)));
typedef uint32_t __attribute__((address_space(3))) lds_u32;
typedef uint32_t __attribute__((address_space(1))) glob_u32;

#define QKV_BLOCKS 384     // 12 n-tiles x 32 m-tiles
#define PAIR_BLOCKS 1024
#define PAIR_ITERS 16      // 1024 blocks x 4 waves x 16 iters x 16 rows = 1M rows
#define NITER  16
#define LOG2E 1.4426950408889634f

// ============ k1: qkv GEMM (inline cast/transpose) || pair bias (3-ahead prefetch) ============
__global__ __launch_bounds__(256) void k1_kernel(
    const float* __restrict__ tokens, const float* __restrict__ pf,
    const float* __restrict__ Wq, const float* __restrict__ Wk,
    const float* __restrict__ Wv, const float* __restrict__ Wp,
    const float* __restrict__ bq, const float* __restrict__ bk,
    const float* __restrict__ bv,
    __bf16* __restrict__ qb, __bf16* __restrict__ kb, __bf16* __restrict__ vtb,
    __bf16* __restrict__ pbb) {
  __shared__ __align__(16) char smem_raw[37504];
  int bx = blockIdx.x, tid = threadIdx.x;
  if (bx < QKV_BLOCKS) {
    // ---- QKV GEMM: dispatched FIRST so compute-bound blocks resident throughout ----
    __bf16 (*As)[40] = (__bf16(*)[40])smem_raw;
    __bf16 (*Bs)[40] = (__bf16(*)[40])(smem_raw + 10240);
    float (*ftile)[133] = (float(*)[133])(smem_raw + 20480);
    const float qscale = 0.125f * LOG2E;
    int nb = bx % 12, mb = bx / 12;
    int m0 = mb * 128, n0 = nb * 128;
    int sel = n0 >> 9, cloc = n0 & 511;
    const float* W = sel == 0 ? Wq : sel == 1 ? Wk : Wv;
    int wave = tid >> 6, lane = tid & 63;
    int wm = (wave >> 1) * 64, wn = (wave & 1) * 64;
    int lg = lane >> 4, lr = lane & 15;
    f32x4 acc[4][4];
#pragma unroll
    for (int i = 0; i < 4; ++i)
#pragma unroll
      for (int j = 0; j < 4; ++j) acc[i][j] = (f32x4){0.f, 0.f, 0.f, 0.f};

    for (int k0 = 0; k0 < 512; k0 += 32) {
      __syncthreads();
#pragma unroll
      for (int i = 0; i < 2; ++i) {
        int cid = tid + i * 256;
        int row = cid >> 2, c8 = (cid & 3) * 8;
        const float* src = &tokens[(size_t)(m0 + row) * 512 + k0 + c8];
        f32x4 f0 = *(const f32x4*)src, f1 = *(const f32x4*)(src + 4);
        bf16x8 vv;
#pragma unroll
        for (int u = 0; u < 4; ++u) { vv[u] = (__bf16)f0[u]; vv[u + 4] = (__bf16)f1[u]; }
        *(bf16x8*)&As[row][c8] = vv;
      }
#pragma unroll
      for (int i = 0; i < 2; ++i) {
        int cid = tid + i * 256;
        int kk = cid >> 4, n8 = (cid & 15) * 8;
        const float* src = &W[(size_t)(k0 + kk) * 512 + cloc + n8];
        *(f32x4*)&ftile[kk][n8] = *(const f32x4*)src;
        *(f32x4*)&ftile[kk][n8 + 4] = *(const f32x4*)(src + 4);
      }
      __syncthreads();
#pragma unroll
      for (int i = 0; i < 2; ++i) {
        int cid = tid + i * 256;
        int n = cid >> 2, kk8 = (cid & 3) * 8;
        bf16x8 vv;
#pragma unroll
        for (int u = 0; u < 8; ++u) vv[u] = (__bf16)ftile[kk8 + u][n];
        *(bf16x8*)&Bs[n][kk8] = vv;
      }
      __syncthreads();
      bf16x8 af[4], bfr[4];
#pragma unroll
      for (int i = 0; i < 4; ++i) {
        af[i]  = *(const bf16x8*)&As[wm + i * 16 + lr][lg * 8];
        bfr[i] = *(const bf16x8*)&Bs[wn + i * 16 + lr][lg * 8];
      }
#pragma unroll
      for (int i = 0; i < 4; ++i)
#pragma unroll
        for (int j = 0; j < 4; ++j)
          acc[i][j] = __builtin_amdgcn_mfma_f32_16x16x32_bf16(af[i], bfr[j], acc[i][j], 0, 0, 0);
    }
#pragma unroll
    for (int i = 0; i < 4; ++i)
#pragma unroll
      for (int j = 0; j < 4; ++j) {
        int grow0 = m0 + wm + i * 16 + lg * 4;
        int gcol = n0 + wn + j * 16 + lr;
        int gsel = gcol >> 9, c = gcol & 511;
        int hh = c >> 6, dd = c & 63;
        int b = grow0 >> 10, n = grow0 & 1023;
        if (gsel == 2) {
          float bias = bv[c];
          bf16x4 pack;
#pragma unroll
          for (int r = 0; r < 4; ++r) pack[r] = (__bf16)(acc[i][j][r] + bias);
          *(bf16x4*)&vtb[(((size_t)(b * 8 + hh)) * 64 + dd) * 1024 + n] = pack;
        } else if (gsel == 0) {
          float bias = bq[c];
#pragma unroll
          for (int r = 0; r < 4; ++r)
            qb[(((size_t)(b * 8 + hh)) * 1024 + n + r) * 64 + dd] = (__bf16)((acc[i][j][r] + bias) * qscale);
        } else {
          float bias = bk[c];
#pragma unroll
          for (int r = 0; r < 4; ++r)
            kb[(((size_t)(b * 8 + hh)) * 1024 + n + r) * 64 + dd] = (__bf16)(acc[i][j][r] + bias);
        }
      }
  } else {
    // ---- pair bias: contiguous 1KB loads, 3-AHEAD register prefetch (4-slot ring) ----
    // pb[h][nm] = LOG2E * sum_p pf[nm][p] * Wp[p][h]; 16 iters/block (prologue amortized)
    int pb = bx - QKV_BLOCKS;
    int wave = tid >> 6, lane = tid & 63;
    int lg = lane >> 4, lr = lane & 15;
    bf16x8 wfrag[2];
#pragma unroll
    for (int s = 0; s < 2; ++s)
#pragma unroll
      for (int j = 0; j < 8; ++j) {
        int p = s * 32 + lg * 8 + j;
        wfrag[s][j] = (lr < 8) ? (__bf16)Wp[p * 8 + lr] : (__bf16)0.f;
      }
    char* psbase = smem_raw + wave * 4096;
    int wbase = pb * 1024 + wave * 256;     // each wave: 256 rows = 16 iters x 16 rows
    int wrow_lo = lane >> 4;
    int wcol = lane & 15;

    f32x4 v[4][4];
    auto PLOAD = [&](int it, int slot) {
      const float* base = pf + (size_t)(wbase + it * 16) * 64;
#pragma unroll
      for (int j = 0; j < 4; ++j)
        v[slot][j] = *(const f32x4*)(base + j * 256 + lane * 4);   // wave: contiguous 1KB
    };
    auto PWLDS = [&](int it, int slot) {
      char* ps = psbase + (it & 1) * 2048;
#pragma unroll
      for (int j = 0; j < 4; ++j) {
        int jr = j * 4 + wrow_lo;
        bf16x4 b;
#pragma unroll
        for (int u = 0; u < 4; ++u) b[u] = (__bf16)v[slot][j][u];
        int cbyte = ((((wcol >> 1) ^ (jr & 7)) << 4) | ((wcol & 1) << 3));
        *(bf16x4*)(ps + jr * 128 + cbyte) = b;
      }
    };
    auto PCOMP = [&](int it) {
      char* ps = psbase + (it & 1) * 2048;
      bf16x8 af[2];
#pragma unroll
      for (int s = 0; s < 2; ++s) {
        int cb = ((s * 4 + lg) ^ (lr & 7)) << 4;
        af[s] = *(const bf16x8*)(ps + lr * 128 + cb);
      }
      f32x4 acc = {0.f, 0.f, 0.f, 0.f};
      acc = __builtin_amdgcn_mfma_f32_16x16x32_bf16(af[0], wfrag[0], acc, 0, 0, 0);
      acc = __builtin_amdgcn_mfma_f32_16x16x32_bf16(af[1], wfrag[1], acc, 0, 0, 0);
      if (lr < 8) {   // D: col=lr=h, row=lg*4+r
        bf16x4 pk;
#pragma unroll
        for (int r = 0; r < 4; ++r) pk[r] = (__bf16)(acc[r] * LOG2E);
        *(bf16x4*)&pbb[((size_t)lr << 20) + wbase + it * 16 + lg * 4] = pk;
      }
    };

    PLOAD(0, 0);
    PLOAD(1, 1);
    PLOAD(2, 2);
#pragma unroll 4
    for (int it = 0; it < PAIR_ITERS; ++it) {
      if (it + 3 < PAIR_ITERS) PLOAD(it + 3, (it + 3) & 3);   // 3 iterations of loads in flight
      PWLDS(it, it & 3);
      PCOMP(it);
    }
  }
}

// ============ k2: flash, single-pass (no split): LDS-staged dbuf, swizzled, writes merged ======
__device__ __forceinline__ bf16x8 swz_read(const __bf16* buf, int r, int k) {
  int chunk = (r << 3) | (k ^ (r & 7));
  return *(const bf16x8*)&buf[chunk * 8];
}

__global__ __launch_bounds__(256) void flash_kernel(const __bf16* __restrict__ qg,
                                                    const __bf16* __restrict__ kg,
                                                    const __bf16* __restrict__ vtg,
                                                    const __bf16* __restrict__ pbg,
                                                    __bf16* __restrict__ merged) {
  __shared__ __align__(16) __bf16 kvs[2][2][64 * 64];
  __shared__ __bf16 pls[4][16][72];
  int bh = blockIdx.y, b = bh >> 3, h = bh & 7;
  int q0 = blockIdx.x * 64;
  int tid = threadIdx.x, wave = tid >> 6, lane = tid & 63;
  int lg = lane >> 4, lr = lane & 15;
  const __bf16* qp = qg + (size_t)bh * 65536;
  const __bf16* kp = kg + (size_t)bh * 65536;
  const __bf16* vp = vtg + (size_t)bh * 65536;
  const __bf16* pbh = pbg + ((size_t)h << 20);
  int qw0 = q0 + wave * 16;

  auto stage = [&](int buf, int kb2) {
#pragma unroll
    for (int p = 0; p < 2; ++p) {
      int c = p * 256 + wave * 64 + lane;
      int r = c >> 3, kk = c & 7;
      int g = (c & ~7) | (kk ^ (r & 7));
      const __bf16* gk = kp + (size_t)kb2 * 4096 + g * 8;
      const __bf16* gv = vp + (size_t)(g >> 3) * 1024 + kb2 * 64 + (g & 7) * 8;
      __builtin_amdgcn_global_load_lds((const glob_u32*)gk,
          (lds_u32*)&kvs[buf][0][(size_t)(p * 256 + wave * 64) * 8], 16, 0, 0);
      __builtin_amdgcn_global_load_lds((const glob_u32*)gv,
          (lds_u32*)&kvs[buf][1][(size_t)(p * 256 + wave * 64) * 8], 16, 0, 0);
    }
  };

  bf16x8 qf[2];
#pragma unroll
  for (int c = 0; c < 2; ++c)
    qf[c] = *(const bf16x8*)&qp[(size_t)(qw0 + lr) * 64 + c * 32 + lg * 8];

  float mrow = -1e30f, lrow = 0.f;
  f32x4 of[4] = {};

  stage(0, 0);
  __syncthreads();

#pragma unroll
  for (int t = 0; t < NITER; ++t) {
    if (t + 1 < NITER) stage((t + 1) & 1, t + 1);
    const __bf16* kbuf = &kvs[t & 1][0][0];
    const __bf16* vbuf = &kvs[t & 1][1][0];

    bf16x8 kf[4][2];
#pragma unroll
    for (int n = 0; n < 4; ++n)
#pragma unroll
      for (int c = 0; c < 2; ++c)
        kf[n][c] = swz_read(kbuf, n * 16 + lr, c * 4 + lg);

    f32x4 sv[4];
#pragma unroll
    for (int n = 0; n < 4; ++n) {
      bf16x4 bias = *(const bf16x4*)&pbh[(size_t)(qw0 + lr) * 1024 + t * 64 + n * 16 + lg * 4];
      f32x4 cb;
#pragma unroll
      for (int r = 0; r < 4; ++r) cb[r] = (float)bias[r];
      cb = __builtin_amdgcn_mfma_f32_16x16x32_bf16(kf[n][0], qf[0], cb, 0, 0, 0);
      cb = __builtin_amdgcn_mfma_f32_16x16x32_bf16(kf[n][1], qf[1], cb, 0, 0, 0);
      sv[n] = cb;
    }

    float tm = -1e30f;
#pragma unroll
    for (int n = 0; n < 4; ++n)
#pragma unroll
      for (int r = 0; r < 4; ++r) tm = fmaxf(tm, sv[n][r]);
    tm = fmaxf(tm, __shfl_xor(tm, 16));
    tm = fmaxf(tm, __shfl_xor(tm, 32));
    float newm = fmaxf(mrow, tm);
    float fs = exp2f(mrow - newm);
    mrow = newm;
    float rs = 0.f;
#pragma unroll
    for (int n = 0; n < 4; ++n)
#pragma unroll
      for (int r = 0; r < 4; ++r) {
        float p = exp2f(sv[n][r] - newm);
        sv[n][r] = p;
        rs += p;
      }
    rs += __shfl_xor(rs, 16);
    rs += __shfl_xor(rs, 32);
    lrow = lrow * fs + rs;

#pragma unroll
    for (int n = 0; n < 4; ++n) {
      bf16x4 pk;
#pragma unroll
      for (int r = 0; r < 4; ++r) pk[r] = (__bf16)sv[n][r];
      *(bf16x4*)&pls[wave][lr][n * 16 + lg * 4] = pk;
    }

#pragma unroll
    for (int r = 0; r < 4; ++r) {
      float fsq = __shfl(fs, (lane & 48) | (lg * 4 + r));
#pragma unroll
      for (int dn = 0; dn < 4; ++dn) of[dn][r] *= fsq;
    }

    bf16x8 pa[2];
#pragma unroll
    for (int c = 0; c < 2; ++c)
      pa[c] = *(const bf16x8*)&pls[wave][lr][c * 32 + lg * 8];
    bf16x8 vf[4][2];
#pragma unroll
    for (int dn = 0; dn < 4; ++dn)
#pragma unroll
      for (int c = 0; c < 2; ++c)
        vf[dn][c] = swz_read(vbuf, dn * 16 + lr, c * 4 + lg);
#pragma unroll
    for (int dn = 0; dn < 4; ++dn) {
      of[dn] = __builtin_amdgcn_mfma_f32_16x16x32_bf16(pa[0], vf[dn][0], of[dn], 0, 0, 0);
      of[dn] = __builtin_amdgcn_mfma_f32_16x16x32_bf16(pa[1], vf[dn][1], of[dn], 0, 0, 0);
    }
    __syncthreads();
  }

  // epilogue: normalize and store merged bf16 [b*N+q][h*64+d]
#pragma unroll
  for (int r = 0; r < 4; ++r) {
    float linv = 1.f / __shfl(lrow, (lane & 48) | (lg * 4 + r));
    int q = qw0 + lg * 4 + r;
#pragma unroll
    for (int dn = 0; dn < 4; ++dn) {
      int dd = dn * 16 + lr;
      merged[((size_t)(b * 1024 + q)) * 512 + h * 64 + dd] = (__bf16)(of[dn][r] * linv);
    }
  }
}

// ============ k3: output projection GEMM (inline Wo transpose), fp32 out + bias ============
__global__ __launch_bounds__(256) void out_gemm_kernel(const __bf16* __restrict__ A,
                                                       const float* __restrict__ Wo,
                                                       const float* __restrict__ bo,
                                                       float* __restrict__ out) {
  __shared__ __bf16 As[128][40];
  __shared__ __bf16 Bs[128][40];
  __shared__ float ftile[32][133];
  int m0 = blockIdx.y * 128, n0 = blockIdx.x * 128;
  int tid = threadIdx.x, wave = tid >> 6, lane = tid & 63;
  int wm = (wave >> 1) * 64, wn = (wave & 1) * 64, lg = lane >> 4, lr = lane & 15;
  f32x4 acc[4][4];
#pragma unroll
  for (int i = 0; i < 4; ++i)
#pragma unroll
    for (int j = 0; j < 4; ++j) acc[i][j] = (f32x4){0.f, 0.f, 0.f, 0.f};

  for (int k0 = 0; k0 < 512; k0 += 32) {
    __syncthreads();
#pragma unroll
    for (int i = 0; i < 2; ++i) {
      int cid = tid + i * 256;
      int row = cid >> 2, c8 = (cid & 3) * 8;
      *(bf16x8*)&As[row][c8] = *(const bf16x8*)&A[(size_t)(m0 + row) * 512 + k0 + c8];
    }
#pragma unroll
    for (int i = 0; i < 2; ++i) {
      int cid = tid + i * 256;
      int kk = cid >> 4, n8 = (cid & 15) * 8;
      const float* src = &Wo[(size_t)(k0 + kk) * 512 + n0 + n8];
      *(f32x4*)&ftile[kk][n8] = *(const f32x4*)src;
      *(f32x4*)&ftile[kk][n8 + 4] = *(const f32x4*)(src + 4);
    }
    __syncthreads();
#pragma unroll
    for (int i = 0; i < 2; ++i) {
      int cid = tid + i * 256;
      int n = cid >> 2, kk8 = (cid & 3) * 8;
      bf16x8 v;
#pragma unroll
      for (int u = 0; u < 8; ++u) v[u] = (__bf16)ftile[kk8 + u][n];
      *(bf16x8*)&Bs[n][kk8] = v;
    }
    __syncthreads();
    bf16x8 af[4], bfr[4];
#pragma unroll
    for (int i = 0; i < 4; ++i) {
      af[i]  = *(const bf16x8*)&As[wm + i * 16 + lr][lg * 8];
      bfr[i] = *(const bf16x8*)&Bs[wn + i * 16 + lr][lg * 8];
    }
#pragma unroll
    for (int i = 0; i < 4; ++i)
#pragma unroll
      for (int j = 0; j < 4; ++j)
        acc[i][j] = __builtin_amdgcn_mfma_f32_16x16x32_bf16(af[i], bfr[j], acc[i][j], 0, 0, 0);
  }
#pragma unroll
  for (int i = 0; i < 4; ++i)
#pragma unroll
    for (int j = 0; j < 4; ++j)
#pragma unroll
      for (int r = 0; r < 4; ++r) {
        int grow = m0 + wm + i * 16 + lg * 4 + r;
        int gcol = n0 + wn + j * 16 + lr;
        out[(size_t)grow * 512 + gcol] = acc[i][j][r] + bo[gcol];
      }
}

extern "C" void kernel_launch(void* const* d_in, const int* in_sizes, int n_in,
                              void* d_out, int out_size, void* d_ws, size_t ws_size,
                              hipStream_t stream) {
  const float* tokens = (const float*)d_in[0];
  const float* pf     = (const float*)d_in[1];
  const float* Wq     = (const float*)d_in[2];
  const float* bq     = (const float*)d_in[3];
  const float* Wk     = (const float*)d_in[4];
  const float* bk     = (const float*)d_in[5];
  const float* Wv     = (const float*)d_in[6];
  const float* bv     = (const float*)d_in[7];
  const float* Wo     = (const float*)d_in[8];
  const float* bo     = (const float*)d_in[9];
  const float* Wp     = (const float*)d_in[10];
  float* out = (float*)d_out;

  char* ws = (char*)d_ws;
  size_t off = 0;
  auto alloc = [&](size_t bytes) { char* p = ws + off; off += (bytes + 255) & ~(size_t)255; return p; };
  __bf16* qb     = (__bf16*)alloc((size_t)32 * 1024 * 64 * 2);
  __bf16* kb     = (__bf16*)alloc((size_t)32 * 1024 * 64 * 2);
  __bf16* vtb    = (__bf16*)alloc((size_t)32 * 64 * 1024 * 2);
  __bf16* pbb    = (__bf16*)alloc((size_t)8 * 1024 * 1024 * 2);
  __bf16* merged = (__bf16*)alloc((size_t)4096 * 512 * 2);

  k1_kernel<<<QKV_BLOCKS + PAIR_BLOCKS, 256, 0, stream>>>(
      tokens, pf, Wq, Wk, Wv, Wp, bq, bk, bv, qb, kb, vtb, pbb);
  flash_kernel<<<dim3(16, 32), 256, 0, stream>>>(qb, kb, vtb, pbb, merged);
  out_gemm_kernel<<<dim3(4, 32), 256, 0, stream>>>(merged, Wo, bo, out);
}

// Round 21
// 118.856 us; speedup vs baseline: 1.0744x; 1.0744x over previous
//
#include <hip/hip_runtime.h>
#include <hip/hip_bf16.h>
#include <stdint.h>
#include <stddef.h>

typedef __bf16 bf16x8 __attribute__((ext_vector_type(8)));
typedef __bf16 bf16x4 __attribute__((ext_vector_type(4)));
typedef float  f32x4  __attribute__((ext_vector_type(4)));
typedef uint32_t __attribute__((address_space(3))) lds_u32;
typedef uint32_t __attribute__((address_space(1))) glob_u32;

#define QKV_BLOCKS 384     // 12 n-tiles x 32 m-tiles
#define PAIR_BLOCKS 2048
#define NITER  16
#define LOG2E 1.4426950408889634f

// ============ k1: qkv GEMM (inline cast/transpose) || pair bias (3-ahead prefetch) ============
__global__ __launch_bounds__(256) void k1_kernel(
    const float* __restrict__ tokens, const float* __restrict__ pf,
    const float* __restrict__ Wq, const float* __restrict__ Wk,
    const float* __restrict__ Wv, const float* __restrict__ Wp,
    const float* __restrict__ bq, const float* __restrict__ bk,
    const float* __restrict__ bv,
    __bf16* __restrict__ qb, __bf16* __restrict__ kb, __bf16* __restrict__ vtb,
    __bf16* __restrict__ pbb) {
  __shared__ __align__(16) char smem_raw[37504];
  int bx = blockIdx.x, tid = threadIdx.x;
  if (bx < QKV_BLOCKS) {
    // ---- QKV GEMM: dispatched FIRST so compute-bound blocks resident throughout ----
    __bf16 (*As)[40] = (__bf16(*)[40])smem_raw;
    __bf16 (*Bs)[40] = (__bf16(*)[40])(smem_raw + 10240);
    float (*ftile)[133] = (float(*)[133])(smem_raw + 20480);
    const float qscale = 0.125f * LOG2E;
    int nb = bx % 12, mb = bx / 12;
    int m0 = mb * 128, n0 = nb * 128;
    int sel = n0 >> 9, cloc = n0 & 511;
    const float* W = sel == 0 ? Wq : sel == 1 ? Wk : Wv;
    int wave = tid >> 6, lane = tid & 63;
    int wm = (wave >> 1) * 64, wn = (wave & 1) * 64;
    int lg = lane >> 4, lr = lane & 15;
    f32x4 acc[4][4];
#pragma unroll
    for (int i = 0; i < 4; ++i)
#pragma unroll
      for (int j = 0; j < 4; ++j) acc[i][j] = (f32x4){0.f, 0.f, 0.f, 0.f};

    for (int k0 = 0; k0 < 512; k0 += 32) {
      __syncthreads();
#pragma unroll
      for (int i = 0; i < 2; ++i) {
        int cid = tid + i * 256;
        int row = cid >> 2, c8 = (cid & 3) * 8;
        const float* src = &tokens[(size_t)(m0 + row) * 512 + k0 + c8];
        f32x4 f0 = *(const f32x4*)src, f1 = *(const f32x4*)(src + 4);
        bf16x8 vv;
#pragma unroll
        for (int u = 0; u < 4; ++u) { vv[u] = (__bf16)f0[u]; vv[u + 4] = (__bf16)f1[u]; }
        *(bf16x8*)&As[row][c8] = vv;
      }
#pragma unroll
      for (int i = 0; i < 2; ++i) {
        int cid = tid + i * 256;
        int kk = cid >> 4, n8 = (cid & 15) * 8;
        const float* src = &W[(size_t)(k0 + kk) * 512 + cloc + n8];
        *(f32x4*)&ftile[kk][n8] = *(const f32x4*)src;
        *(f32x4*)&ftile[kk][n8 + 4] = *(const f32x4*)(src + 4);
      }
      __syncthreads();
#pragma unroll
      for (int i = 0; i < 2; ++i) {
        int cid = tid + i * 256;
        int n = cid >> 2, kk8 = (cid & 3) * 8;
        bf16x8 vv;
#pragma unroll
        for (int u = 0; u < 8; ++u) vv[u] = (__bf16)ftile[kk8 + u][n];
        *(bf16x8*)&Bs[n][kk8] = vv;
      }
      __syncthreads();
      bf16x8 af[4], bfr[4];
#pragma unroll
      for (int i = 0; i < 4; ++i) {
        af[i]  = *(const bf16x8*)&As[wm + i * 16 + lr][lg * 8];
        bfr[i] = *(const bf16x8*)&Bs[wn + i * 16 + lr][lg * 8];
      }
#pragma unroll
      for (int i = 0; i < 4; ++i)
#pragma unroll
        for (int j = 0; j < 4; ++j)
          acc[i][j] = __builtin_amdgcn_mfma_f32_16x16x32_bf16(af[i], bfr[j], acc[i][j], 0, 0, 0);
    }
#pragma unroll
    for (int i = 0; i < 4; ++i)
#pragma unroll
      for (int j = 0; j < 4; ++j) {
        int grow0 = m0 + wm + i * 16 + lg * 4;
        int gcol = n0 + wn + j * 16 + lr;
        int gsel = gcol >> 9, c = gcol & 511;
        int hh = c >> 6, dd = c & 63;
        int b = grow0 >> 10, n = grow0 & 1023;
        if (gsel == 2) {
          float bias = bv[c];
          bf16x4 pack;
#pragma unroll
          for (int r = 0; r < 4; ++r) pack[r] = (__bf16)(acc[i][j][r] + bias);
          *(bf16x4*)&vtb[(((size_t)(b * 8 + hh)) * 64 + dd) * 1024 + n] = pack;
        } else if (gsel == 0) {
          float bias = bq[c];
#pragma unroll
          for (int r = 0; r < 4; ++r)
            qb[(((size_t)(b * 8 + hh)) * 1024 + n + r) * 64 + dd] = (__bf16)((acc[i][j][r] + bias) * qscale);
        } else {
          float bias = bk[c];
#pragma unroll
          for (int r = 0; r < 4; ++r)
            kb[(((size_t)(b * 8 + hh)) * 1024 + n + r) * 64 + dd] = (__bf16)(acc[i][j][r] + bias);
        }
      }
  } else {
    // ---- pair bias: contiguous 1KB loads, 3-AHEAD register prefetch (4-slot ring) ----
    // pb[h][nm] = LOG2E * sum_p pf[nm][p] * Wp[p][h]
    int pb = bx - QKV_BLOCKS;
    int wave = tid >> 6, lane = tid & 63;
    int lg = lane >> 4, lr = lane & 15;
    bf16x8 wfrag[2];
#pragma unroll
    for (int s = 0; s < 2; ++s)
#pragma unroll
      for (int j = 0; j < 8; ++j) {
        int p = s * 32 + lg * 8 + j;
        wfrag[s][j] = (lr < 8) ? (__bf16)Wp[p * 8 + lr] : (__bf16)0.f;
      }
    char* psbase = smem_raw + wave * 4096;
    int wbase = pb * 512 + wave * 128;
    int wrow_lo = lane >> 4;
    int wcol = lane & 15;

    f32x4 v[4][4];
    auto PLOAD = [&](int it, int slot) {
      const float* base = pf + (size_t)(wbase + it * 16) * 64;
#pragma unroll
      for (int j = 0; j < 4; ++j)
        v[slot][j] = *(const f32x4*)(base + j * 256 + lane * 4);   // wave: contiguous 1KB
    };
    auto PWLDS = [&](int it, int slot) {
      char* ps = psbase + (it & 1) * 2048;
#pragma unroll
      for (int j = 0; j < 4; ++j) {
        int jr = j * 4 + wrow_lo;
        bf16x4 b;
#pragma unroll
        for (int u = 0; u < 4; ++u) b[u] = (__bf16)v[slot][j][u];
        int cbyte = ((((wcol >> 1) ^ (jr & 7)) << 4) | ((wcol & 1) << 3));
        *(bf16x4*)(ps + jr * 128 + cbyte) = b;
      }
    };
    auto PCOMP = [&](int it) {
      char* ps = psbase + (it & 1) * 2048;
      bf16x8 af[2];
#pragma unroll
      for (int s = 0; s < 2; ++s) {
        int cb = ((s * 4 + lg) ^ (lr & 7)) << 4;
        af[s] = *(const bf16x8*)(ps + lr * 128 + cb);
      }
      f32x4 acc = {0.f, 0.f, 0.f, 0.f};
      acc = __builtin_amdgcn_mfma_f32_16x16x32_bf16(af[0], wfrag[0], acc, 0, 0, 0);
      acc = __builtin_amdgcn_mfma_f32_16x16x32_bf16(af[1], wfrag[1], acc, 0, 0, 0);
      if (lr < 8) {   // D: col=lr=h, row=lg*4+r
        bf16x4 pk;
#pragma unroll
        for (int r = 0; r < 4; ++r) pk[r] = (__bf16)(acc[r] * LOG2E);
        *(bf16x4*)&pbb[((size_t)lr << 20) + wbase + it * 16 + lg * 4] = pk;
      }
    };

    PLOAD(0, 0);
    PLOAD(1, 1);
    PLOAD(2, 2);
#pragma unroll
    for (int it = 0; it < 8; ++it) {
      if (it + 3 < 8) PLOAD(it + 3, (it + 3) & 3);   // 3 iterations of loads in flight
      PWLDS(it, it & 3);
      PCOMP(it);
    }
  }
}

// ============ k2: flash, single-pass (no split): LDS-staged dbuf, swizzled, writes merged ======
__device__ __forceinline__ bf16x8 swz_read(const __bf16* buf, int r, int k) {
  int chunk = (r << 3) | (k ^ (r & 7));
  return *(const bf16x8*)&buf[chunk * 8];
}

__global__ __launch_bounds__(256) void flash_kernel(const __bf16* __restrict__ qg,
                                                    const __bf16* __restrict__ kg,
                                                    const __bf16* __restrict__ vtg,
                                                    const __bf16* __restrict__ pbg,
                                                    __bf16* __restrict__ merged) {
  __shared__ __align__(16) __bf16 kvs[2][2][64 * 64];
  __shared__ __bf16 pls[4][16][72];
  int bh = blockIdx.y, b = bh >> 3, h = bh & 7;
  int q0 = blockIdx.x * 64;
  int tid = threadIdx.x, wave = tid >> 6, lane = tid & 63;
  int lg = lane >> 4, lr = lane & 15;
  const __bf16* qp = qg + (size_t)bh * 65536;
  const __bf16* kp = kg + (size_t)bh * 65536;
  const __bf16* vp = vtg + (size_t)bh * 65536;
  const __bf16* pbh = pbg + ((size_t)h << 20);
  int qw0 = q0 + wave * 16;

  auto stage = [&](int buf, int kb2) {
#pragma unroll
    for (int p = 0; p < 2; ++p) {
      int c = p * 256 + wave * 64 + lane;
      int r = c >> 3, kk = c & 7;
      int g = (c & ~7) | (kk ^ (r & 7));
      const __bf16* gk = kp + (size_t)kb2 * 4096 + g * 8;
      const __bf16* gv = vp + (size_t)(g >> 3) * 1024 + kb2 * 64 + (g & 7) * 8;
      __builtin_amdgcn_global_load_lds((const glob_u32*)gk,
          (lds_u32*)&kvs[buf][0][(size_t)(p * 256 + wave * 64) * 8], 16, 0, 0);
      __builtin_amdgcn_global_load_lds((const glob_u32*)gv,
          (lds_u32*)&kvs[buf][1][(size_t)(p * 256 + wave * 64) * 8], 16, 0, 0);
    }
  };

  bf16x8 qf[2];
#pragma unroll
  for (int c = 0; c < 2; ++c)
    qf[c] = *(const bf16x8*)&qp[(size_t)(qw0 + lr) * 64 + c * 32 + lg * 8];

  float mrow = -1e30f, lrow = 0.f;
  f32x4 of[4] = {};

  stage(0, 0);
  __syncthreads();

#pragma unroll
  for (int t = 0; t < NITER; ++t) {
    if (t + 1 < NITER) stage((t + 1) & 1, t + 1);
    const __bf16* kbuf = &kvs[t & 1][0][0];
    const __bf16* vbuf = &kvs[t & 1][1][0];

    bf16x8 kf[4][2];
#pragma unroll
    for (int n = 0; n < 4; ++n)
#pragma unroll
      for (int c = 0; c < 2; ++c)
        kf[n][c] = swz_read(kbuf, n * 16 + lr, c * 4 + lg);

    f32x4 sv[4];
#pragma unroll
    for (int n = 0; n < 4; ++n) {
      bf16x4 bias = *(const bf16x4*)&pbh[(size_t)(qw0 + lr) * 1024 + t * 64 + n * 16 + lg * 4];
      f32x4 cb;
#pragma unroll
      for (int r = 0; r < 4; ++r) cb[r] = (float)bias[r];
      cb = __builtin_amdgcn_mfma_f32_16x16x32_bf16(kf[n][0], qf[0], cb, 0, 0, 0);
      cb = __builtin_amdgcn_mfma_f32_16x16x32_bf16(kf[n][1], qf[1], cb, 0, 0, 0);
      sv[n] = cb;
    }

    float tm = -1e30f;
#pragma unroll
    for (int n = 0; n < 4; ++n)
#pragma unroll
      for (int r = 0; r < 4; ++r) tm = fmaxf(tm, sv[n][r]);
    tm = fmaxf(tm, __shfl_xor(tm, 16));
    tm = fmaxf(tm, __shfl_xor(tm, 32));
    float newm = fmaxf(mrow, tm);
    float fs = exp2f(mrow - newm);
    mrow = newm;
    float rs = 0.f;
#pragma unroll
    for (int n = 0; n < 4; ++n)
#pragma unroll
      for (int r = 0; r < 4; ++r) {
        float p = exp2f(sv[n][r] - newm);
        sv[n][r] = p;
        rs += p;
      }
    rs += __shfl_xor(rs, 16);
    rs += __shfl_xor(rs, 32);
    lrow = lrow * fs + rs;

#pragma unroll
    for (int n = 0; n < 4; ++n) {
      bf16x4 pk;
#pragma unroll
      for (int r = 0; r < 4; ++r) pk[r] = (__bf16)sv[n][r];
      *(bf16x4*)&pls[wave][lr][n * 16 + lg * 4] = pk;
    }

#pragma unroll
    for (int r = 0; r < 4; ++r) {
      float fsq = __shfl(fs, (lane & 48) | (lg * 4 + r));
#pragma unroll
      for (int dn = 0; dn < 4; ++dn) of[dn][r] *= fsq;
    }

    bf16x8 pa[2];
#pragma unroll
    for (int c = 0; c < 2; ++c)
      pa[c] = *(const bf16x8*)&pls[wave][lr][c * 32 + lg * 8];
    bf16x8 vf[4][2];
#pragma unroll
    for (int dn = 0; dn < 4; ++dn)
#pragma unroll
      for (int c = 0; c < 2; ++c)
        vf[dn][c] = swz_read(vbuf, dn * 16 + lr, c * 4 + lg);
#pragma unroll
    for (int dn = 0; dn < 4; ++dn) {
      of[dn] = __builtin_amdgcn_mfma_f32_16x16x32_bf16(pa[0], vf[dn][0], of[dn], 0, 0, 0);
      of[dn] = __builtin_amdgcn_mfma_f32_16x16x32_bf16(pa[1], vf[dn][1], of[dn], 0, 0, 0);
    }
    __syncthreads();
  }

  // epilogue: normalize and store merged bf16 [b*N+q][h*64+d]
#pragma unroll
  for (int r = 0; r < 4; ++r) {
    float linv = 1.f / __shfl(lrow, (lane & 48) | (lg * 4 + r));
    int q = qw0 + lg * 4 + r;
#pragma unroll
    for (int dn = 0; dn < 4; ++dn) {
      int dd = dn * 16 + lr;
      merged[((size_t)(b * 1024 + q)) * 512 + h * 64 + dd] = (__bf16)(of[dn][r] * linv);
    }
  }
}

// ============ k3: output projection GEMM (inline Wo transpose), fp32 out + bias ============
__global__ __launch_bounds__(256) void out_gemm_kernel(const __bf16* __restrict__ A,
                                                       const float* __restrict__ Wo,
                                                       const float* __restrict__ bo,
                                                       float* __restrict__ out) {
  __shared__ __bf16 As[128][40];
  __shared__ __bf16 Bs[128][40];
  __shared__ float ftile[32][133];
  int m0 = blockIdx.y * 128, n0 = blockIdx.x * 128;
  int tid = threadIdx.x, wave = tid >> 6, lane = tid & 63;
  int wm = (wave >> 1) * 64, wn = (wave & 1) * 64, lg = lane >> 4, lr = lane & 15;
  f32x4 acc[4][4];
#pragma unroll
  for (int i = 0; i < 4; ++i)
#pragma unroll
    for (int j = 0; j < 4; ++j) acc[i][j] = (f32x4){0.f, 0.f, 0.f, 0.f};

  for (int k0 = 0; k0 < 512; k0 += 32) {
    __syncthreads();
#pragma unroll
    for (int i = 0; i < 2; ++i) {
      int cid = tid + i * 256;
      int row = cid >> 2, c8 = (cid & 3) * 8;
      *(bf16x8*)&As[row][c8] = *(const bf16x8*)&A[(size_t)(m0 + row) * 512 + k0 + c8];
    }
#pragma unroll
    for (int i = 0; i < 2; ++i) {
      int cid = tid + i * 256;
      int kk = cid >> 4, n8 = (cid & 15) * 8;
      const float* src = &Wo[(size_t)(k0 + kk) * 512 + n0 + n8];
      *(f32x4*)&ftile[kk][n8] = *(const f32x4*)src;
      *(f32x4*)&ftile[kk][n8 + 4] = *(const f32x4*)(src + 4);
    }
    __syncthreads();
#pragma unroll
    for (int i = 0; i < 2; ++i) {
      int cid = tid + i * 256;
      int n = cid >> 2, kk8 = (cid & 3) * 8;
      bf16x8 v;
#pragma unroll
      for (int u = 0; u < 8; ++u) v[u] = (__bf16)ftile[kk8 + u][n];
      *(bf16x8*)&Bs[n][kk8] = v;
    }
    __syncthreads();
    bf16x8 af[4], bfr[4];
#pragma unroll
    for (int i = 0; i < 4; ++i) {
      af[i]  = *(const bf16x8*)&As[wm + i * 16 + lr][lg * 8];
      bfr[i] = *(const bf16x8*)&Bs[wn + i * 16 + lr][lg * 8];
    }
#pragma unroll
    for (int i = 0; i < 4; ++i)
#pragma unroll
      for (int j = 0; j < 4; ++j)
        acc[i][j] = __builtin_amdgcn_mfma_f32_16x16x32_bf16(af[i], bfr[j], acc[i][j], 0, 0, 0);
  }
#pragma unroll
  for (int i = 0; i < 4; ++i)
#pragma unroll
    for (int j = 0; j < 4; ++j)
#pragma unroll
      for (int r = 0; r < 4; ++r) {
        int grow = m0 + wm + i * 16 + lg * 4 + r;
        int gcol = n0 + wn + j * 16 + lr;
        out[(size_t)grow * 512 + gcol] = acc[i][j][r] + bo[gcol];
      }
}

extern "C" void kernel_launch(void* const* d_in, const int* in_sizes, int n_in,
                              void* d_out, int out_size, void* d_ws, size_t ws_size,
                              hipStream_t stream) {
  const float* tokens = (const float*)d_in[0];
  const float* pf     = (const float*)d_in[1];
  const float* Wq     = (const float*)d_in[2];
  const float* bq     = (const float*)d_in[3];
  const float* Wk     = (const float*)d_in[4];
  const float* bk     = (const float*)d_in[5];
  const float* Wv     = (const float*)d_in[6];
  const float* bv     = (const float*)d_in[7];
  const float* Wo     = (const float*)d_in[8];
  const float* bo     = (const float*)d_in[9];
  const float* Wp     = (const float*)d_in[10];
  float* out = (float*)d_out;

  char* ws = (char*)d_ws;
  size_t off = 0;
  auto alloc = [&](size_t bytes) { char* p = ws + off; off += (bytes + 255) & ~(size_t)255; return p; };
  __bf16* qb     = (__bf16*)alloc((size_t)32 * 1024 * 64 * 2);
  __bf16* kb     = (__bf16*)alloc((size_t)32 * 1024 * 64 * 2);
  __bf16* vtb    = (__bf16*)alloc((size_t)32 * 64 * 1024 * 2);
  __bf16* pbb    = (__bf16*)alloc((size_t)8 * 1024 * 1024 * 2);
  __bf16* merged = (__bf16*)alloc((size_t)4096 * 512 * 2);

  k1_kernel<<<QKV_BLOCKS + PAIR_BLOCKS, 256, 0, stream>>>(
      tokens, pf, Wq, Wk, Wv, Wp, bq, bk, bv, qb, kb, vtb, pbb);
  flash_kernel<<<dim3(16, 32), 256, 0, stream>>>(qb, kb, vtb, pbb, merged);
  out_gemm_kernel<<<dim3(4, 32), 256, 0, stream>>>(merged, Wo, bo, out);
}